// Round 6
// baseline (404.398 us; speedup 1.0000x reference)
//
#include <hip/hip_runtime.h>

// x: (64,3,512,512) fp32 -> conv3x3 VALID + avgpool2x2 + sigmoid + per-batch sum.
// Fused stride-2 4x4 conv: w_eff[ky][kx] = 0.25*sum_{py,px in {0,1}} w[ky-py][kx-px].
//
// R6: oc-LOOP IN-LANE + SGPR WEIGHTS + LDS full-row staging.
//  Lane = pooled col-pair (128 lanes = 256 cols = full row). Block stages whole
//  input row-pairs into LDS (coalesced; ~1x amplification, LDS pipe ~6us total).
//  Per row-pair each lane builds 24 packed v2f col-pairs (xv, 48 VGPRs) ONCE,
//  then loops 16 oc: weights are wave-uniform s_loads consumed as SGPR scalar
//  operands in v_pk_fma_f32 (the only free broadcast path on CDNA) -> the oc
//  loop is pure VGPRxSGPR FMA. Row-streaming {old,new} pending pooled rows
//  (R5-verified recurrence), packed over cols: acc = 16 oc x 2 x v2f = 64 VGPR.
//  Budget/rp/wave: VALU ~2140 cyc (72% FMA), DS ~216, SMEM 3KB. Floor ~30us.

#define IC 3
#define OCH 16
#define HH 512
#define WW 512
#define WP 255      // pooled cols
#define L 15        // pooled rows per strip (255 = 15*17)
#define STRIPS 17
#define RSTRIDE 520 // floats per staged row-plane (512 + 8 pad for lane127 tail)

typedef float v2f __attribute__((ext_vector_type(2)));
typedef float v4f __attribute__((ext_vector_type(4)));

__device__ __forceinline__ float fast_sigmoid(float v) {
    float e = __expf(-v);                    // v_exp_f32
    return __builtin_amdgcn_rcpf(1.0f + e);  // v_rcp_f32
}

// ws: per oc, 64 floats (256B stride, s_load_dwordx16-aligned):
//   [(ky*3+ic)*4 + kx] = w_eff[ky][ic][kx]   (ky,kx in 0..3)
//   [48] = bias[oc]
__global__ void build_weff(const float* __restrict__ w,
                           const float* __restrict__ bias,
                           float* __restrict__ ws)
{
    const int i = threadIdx.x;
    for (int idx = i; idx < OCH * 48; idx += 256) {
        const int oc = idx / 48;
        const int r  = idx - oc * 48;
        const int kx = r & 3;
        const int t2 = r >> 2;        // ky*3+ic
        const int ky = t2 / 3;
        const int ic = t2 - ky * 3;
        float s = 0.f;
#pragma unroll
        for (int py = 0; py < 2; ++py) {
            int rr = ky - py;
            if (rr < 0 || rr > 2) continue;
#pragma unroll
            for (int px = 0; px < 2; ++px) {
                int cc = kx - px;
                if (cc < 0 || cc > 2) continue;
                s += w[((oc * IC + ic) * 3 + rr) * 3 + cc];
            }
        }
        ws[oc * 64 + r] = 0.25f * s;
    }
    if (i < OCH) ws[i * 64 + 48] = bias[i];
}

__global__ __launch_bounds__(128, 3)
void conv_pool_sig_sum(const float* __restrict__ x,
                       const float* __restrict__ wws,
                       float* __restrict__ out)
{
    const int tid = threadIdx.x;          // 0..127: pooled col-pair (cols 2t,2t+1)
    const int b   = blockIdx.y;
    const int r0  = blockIdx.x * L;       // first pooled row of strip

    // staged: [buf][par*IC+ic][RSTRIDE]; 2*6*520*4 = 24.96 KB -> 6 blocks/CU
    __shared__ float sbuf[2][2 * IC * RSTRIDE];
    __shared__ float red[2];

    const float* xg = x + (size_t)b * (IC * HH * WW) + 4 * tid;  // lane col base

    // ---- prologue: stage row-pair 0 (input rows 2r0, 2r0+1) into buf0 ----
    {
        v4f st[6];
#pragma unroll
        for (int pl = 0; pl < 6; ++pl) {
            const int r = pl / 3, ic = pl - 3 * r;
            st[pl] = *(const v4f*)(xg + (size_t)ic * (HH * WW)
                                      + (size_t)(2 * r0 + r) * WW);
        }
#pragma unroll
        for (int pl = 0; pl < 6; ++pl)
            *(v4f*)(&sbuf[0][pl * RSTRIDE + 4 * tid]) = st[pl];
    }
    __syncthreads();

    // acc: {old, new} pending pooled rows, packed over this lane's 2 cols
    v2f ao[OCH], an[OCH];
#pragma unroll
    for (int oc = 0; oc < OCH; ++oc) an[oc] = (v2f){0.f, 0.f};
    float lsA = 0.f, lsB = 0.f;

    // steps t=0..15: input rows 2r0+2t, +1. Emit pooled row r0+t-1 at t>=1.
#pragma unroll 1
    for (int t = 0; t <= L; ++t) {
        const int pp = t & 1;

        // issue stage loads for row-pair t+1 EARLY (hide HBM under oc loop)
        v4f st[6];
        const bool dost = (t < L);
        if (dost) {
#pragma unroll
            for (int pl = 0; pl < 6; ++pl) {
                const int r = pl / 3, ic = pl - 3 * r;
                st[pl] = *(const v4f*)(xg + (size_t)ic * (HH * WW)
                                          + (size_t)(2 * r0 + 2 * t + 2 + r) * WW);
            }
        }

        // build xv col-pairs ONCE per row-pair (reused by all 16 oc):
        // window w[0..5] = input cols 4tid..4tid+5; xv[kx] = {w[kx], w[kx+2]}
        v2f xv[2][IC][4];
#pragma unroll
        for (int par = 0; par < 2; ++par)
#pragma unroll
            for (int ic = 0; ic < IC; ++ic) {
                const float* p = &sbuf[pp][(par * IC + ic) * RSTRIDE + 4 * tid];
                const v4f a  = *(const v4f*)p;
                const v4f bq = *(const v4f*)(p + 4);   // pad keeps lane127 in-bounds
                xv[par][ic][0] = (v2f){a.x, a.z};
                xv[par][ic][1] = (v2f){a.y, a.w};
                xv[par][ic][2] = (v2f){a.z, bq.x};
                xv[par][ic][3] = (v2f){a.w, bq.y};
            }

        // oc loop: rotate, 48 pk-FMA with SGPR-scalar weights, per oc
#pragma unroll
        for (int oc = 0; oc < OCH; ++oc) {
            const float* we = wws + oc * 64;   // wave-uniform -> s_load
            ao[oc] = an[oc];
            const float bv = we[48];
            an[oc] = (v2f){bv, bv};
#pragma unroll
            for (int par = 0; par < 2; ++par)
#pragma unroll
                for (int ic = 0; ic < IC; ++ic)
#pragma unroll
                    for (int kx = 0; kx < 4; ++kx) {
                        const v2f xvv = xv[par][ic][kx];
                        ao[oc] += xvv * we[((par + 2) * IC + ic) * 4 + kx];
                        an[oc] += xvv * we[(par * IC + ic) * 4 + kx];
                    }
        }

        // emit pooled row r0+t-1 (old slots complete after this row-pair)
        if (t > 0) {
#pragma unroll
            for (int oc = 0; oc < OCH; ++oc) {
                lsA += fast_sigmoid(ao[oc].x);
                lsB += fast_sigmoid(ao[oc].y);
            }
        }

        // write staged row-pair to the other buffer; one barrier per step
        if (dost) {
#pragma unroll
            for (int pl = 0; pl < 6; ++pl)
                *(v4f*)(&sbuf[pp ^ 1][pl * RSTRIDE + 4 * tid]) = st[pl];
        }
        __syncthreads();
    }

    if (2 * tid + 1 >= WP) lsB = 0.f;   // pooled col 255 doesn't exist (lane 127)
    float lsum = lsA + lsB;

    // wave64 butterfly -> 2-wave LDS reduce -> one atomic per block
#pragma unroll
    for (int off = 32; off > 0; off >>= 1)
        lsum += __shfl_xor(lsum, off, 64);
    if ((tid & 63) == 0) red[tid >> 6] = lsum;
    __syncthreads();
    if (tid == 0) atomicAdd(out + b, red[0] + red[1]);
}

extern "C" void kernel_launch(void* const* d_in, const int* in_sizes, int n_in,
                              void* d_out, int out_size, void* d_ws, size_t ws_size,
                              hipStream_t stream) {
    const float* x = (const float*)d_in[0];
    const float* w = (const float*)d_in[1];
    const float* bias = (const float*)d_in[2];
    float* out = (float*)d_out;
    float* wws = (float*)d_ws;  // 16 * 64 floats = 4 KB

    hipMemsetAsync(out, 0, out_size * sizeof(float), stream);
    build_weff<<<1, 256, 0, stream>>>(w, bias, wws);

    dim3 grid(STRIPS, 64);  // 17 strips x 64 batches = 1088 blocks x 2 waves
    conv_pool_sig_sum<<<grid, 128, 0, stream>>>(x, wws, out);
}